// Round 8
// baseline (599.708 us; speedup 1.0000x reference)
//
#include <hip/hip_runtime.h>
#include <hip/hip_bf16.h>

#define BB 256
#define NN 512
#define HH 128
#define MM (BB*NN)

typedef unsigned short u16;
typedef unsigned int   u32;
typedef __attribute__((ext_vector_type(8))) short bf16x8;   // 8 bf16 (4 VGPRs)
typedef __attribute__((ext_vector_type(4))) float f32x4;
typedef __attribute__((ext_vector_type(16))) float f32x16;

#define LOG2E  1.4426950408889634f
#define QSCALE (0.125f * LOG2E)       // 1/sqrt(64) folded with log2(e) for exp2
#define NEGB   (-10000.0f * LOG2E)    // mask bias in log2 domain -> exp2 underflows to 0

// byte offset of (row, cbyte) in a [*][64]bf16 (128B-row) LDS tile, XOR-swizzled
__device__ __forceinline__ int kswz(int row, int cbyte) {
  return row*128 + (cbyte ^ ((row & 7) << 4));
}
// same for [*][128]bf16 (256B-row) tiles
__device__ __forceinline__ int wswz(int row, int cbyte) {
  return row*256 + (cbyte ^ ((row & 7) << 4));
}

__device__ __forceinline__ u16 f2bf(float x) {   // f32 -> bf16 RNE
  __hip_bfloat16 h = __float2bfloat16(x);
  return *reinterpret_cast<u16*>(&h);
}
__device__ __forceinline__ float bf2f(u16 x) {
  return __uint_as_float(((u32)x) << 16);
}

// async global->LDS DMA, 16B per lane; LDS dest = wave-uniform base + lane*16.
__device__ __forceinline__ void gld_lds16(const void* g, void* l) {
  __builtin_amdgcn_global_load_lds(
      (__attribute__((address_space(1))) const unsigned int*)g,
      (__attribute__((address_space(3))) unsigned int*)l, 16, 0, 0);
}

// ---------------------------------------------------------------------------
// Pre-transpose + bf16-convert the 11 weight matrices: wt[i] = W_i^T [c][k]
__global__ __launch_bounds__(256) void wt_prep(
    const float* __restrict__ W0, const float* __restrict__ W1,
    const float* __restrict__ Wq, const float* __restrict__ Wk,
    const float* __restrict__ Wv, u16* __restrict__ wt)
{
  __shared__ u16 tile[128*128];
  const int t = threadIdx.x;
  const int i = blockIdx.x;
  const float* src;
  if (i == 0) src = W0;
  else if (i == 1) src = W1;
  else {
    const int d = (i-2)/3, which = (i-2)%3;
    src = (which==0 ? Wq : which==1 ? Wk : Wv) + d*HH*HH;
  }
  u16* dst = wt + (size_t)i*HH*HH;

  #pragma unroll
  for (int j = 0; j < 8; j++) {
    const int chunk = t + 256*j;
    const int k = chunk >> 4, c8 = (chunk & 15)*8;
    const float4 a = *(const float4*)&src[k*HH + c8];
    const float4 b = *(const float4*)&src[k*HH + c8 + 4];
    union { u16 s[8]; uint4 v; } u;
    u.s[0]=f2bf(a.x); u.s[1]=f2bf(a.y); u.s[2]=f2bf(a.z); u.s[3]=f2bf(a.w);
    u.s[4]=f2bf(b.x); u.s[5]=f2bf(b.y); u.s[6]=f2bf(b.z); u.s[7]=f2bf(b.w);
    *(uint4*)&tile[k*128 + (((chunk & 15) ^ ((k>>3)&7)) << 3)] = u.v;
  }
  __syncthreads();
  #pragma unroll
  for (int j = 0; j < 8; j++) {
    const int chunk = t + 256*j;
    const int c = chunk >> 4, kb8 = (chunk & 15)*8;
    union { u16 s[8]; uint4 v; } u;
    #pragma unroll
    for (int e = 0; e < 8; e++) {
      const int k = kb8 + e;
      u.s[e] = tile[k*128 + ((((c>>3) ^ ((k>>3)&7)) << 3) | (c & 7))];
    }
    *(uint4*)&dst[c*HH + kb8] = u.v;
  }
}

// ---------------------------------------------------------------------------
// MLP linears (2 uses): OUT[M,128](bf16) = LNRELU ? relu(LN(X@W+b)) : X@W+b
template<bool F32IN, bool LNRELU>
__global__ __launch_bounds__(256) void linear_mfma(
    const void* __restrict__ Xv, const u16* __restrict__ WT,
    const float* __restrict__ bias, const float* __restrict__ gamma,
    const float* __restrict__ beta, u16* __restrict__ OUT)
{
  __shared__ u16 wt_s[128*128];  // W^T tile, swizzled 32KB
  __shared__ u16 xs[128*128];    // X tile,   swizzled 32KB
  const int t = threadIdx.x;
  const int lane = t & 63, w = t >> 6;
  const int l4 = lane >> 4, l15 = lane & 15;
  const long row0 = (long)blockIdx.x * 128;

  {
    const int rr = lane >> 4;
    const int cb = (lane & 15) * 16;
    #pragma unroll
    for (int i = 0; i < 8; i++) {
      const int seg = w*8 + i;
      const int row = seg*4 + rr;
      gld_lds16((const char*)WT + (size_t)row*256 + (cb ^ ((row & 7) << 4)),
                (char*)wt_s + seg*1024);
    }
    if constexpr (!F32IN) {
      const char* xp = (const char*)((const u16*)Xv + row0*HH);
      #pragma unroll
      for (int i = 0; i < 8; i++) {
        const int seg = w*8 + i;
        const int row = seg*4 + rr;
        gld_lds16(xp + (size_t)row*256 + (cb ^ ((row & 7) << 4)),
                  (char*)xs + seg*1024);
      }
    }
  }
  if constexpr (F32IN) {
    const float* xp = (const float*)Xv + row0*HH;
    #pragma unroll
    for (int i = 0; i < 8; i++) {
      const int chunk = t + 256*i;
      const int r = chunk >> 4, c8 = (chunk & 15)*8;
      const float4 a = *(const float4*)&xp[r*HH + c8];
      const float4 b = *(const float4*)&xp[r*HH + c8 + 4];
      union { u16 s[8]; uint4 v; } u;
      u.s[0]=f2bf(a.x); u.s[1]=f2bf(a.y); u.s[2]=f2bf(a.z); u.s[3]=f2bf(a.w);
      u.s[4]=f2bf(b.x); u.s[5]=f2bf(b.y); u.s[6]=f2bf(b.z); u.s[7]=f2bf(b.w);
      *(uint4*)((char*)xs + wswz(r, c8*2)) = u.v;
    }
  }
  __syncthreads();

  f32x4 acc[2][8];
  #pragma unroll
  for (int m = 0; m < 2; m++)
    #pragma unroll
    for (int n = 0; n < 8; n++)
      { acc[m][n][0]=0.f; acc[m][n][1]=0.f; acc[m][n][2]=0.f; acc[m][n][3]=0.f; }

  #pragma unroll
  for (int ks = 0; ks < 4; ks++) {
    bf16x8 af[2], bf[8];
    #pragma unroll
    for (int m = 0; m < 2; m++)
      af[m] = *(const bf16x8*)((const char*)xs + wswz(w*32 + m*16 + l15, ks*64 + l4*16));
    #pragma unroll
    for (int n = 0; n < 8; n++)
      bf[n] = *(const bf16x8*)((const char*)wt_s + wswz(n*16 + l15, ks*64 + l4*16));
    #pragma unroll
    for (int m = 0; m < 2; m++)
      #pragma unroll
      for (int n = 0; n < 8; n++)
        acc[m][n] = __builtin_amdgcn_mfma_f32_16x16x32_bf16(af[m], bf[n], acc[m][n], 0, 0, 0);
  }

  float bia[8], gam[8], bet[8];
  #pragma unroll
  for (int n = 0; n < 8; n++) {
    bia[n] = bias[n*16 + l15];
    if constexpr (LNRELU) { gam[n] = gamma[n*16 + l15]; bet[n] = beta[n*16 + l15]; }
  }
  #pragma unroll
  for (int m = 0; m < 2; m++) {
    #pragma unroll
    for (int r = 0; r < 4; r++) {
      const long row = row0 + w*32 + m*16 + l4*4 + r;
      float v[8];
      #pragma unroll
      for (int n = 0; n < 8; n++) v[n] = acc[m][n][r] + bia[n];
      if constexpr (LNRELU) {
        float s = 0.f, ss = 0.f;
        #pragma unroll
        for (int n = 0; n < 8; n++) { s += v[n]; ss += v[n]*v[n]; }
        #pragma unroll
        for (int off = 1; off < 16; off <<= 1) {
          s  += __shfl_xor(s,  off);
          ss += __shfl_xor(ss, off);
        }
        const float mean = s * (1.0f/128.0f);
        const float rstd = rsqrtf(ss*(1.0f/128.0f) - mean*mean + 1e-5f);
        #pragma unroll
        for (int n = 0; n < 8; n++)
          v[n] = fmaxf((v[n] - mean)*rstd*gam[n] + bet[n], 0.0f);
      }
      u16* op = OUT + row*HH + l15;
      #pragma unroll
      for (int n = 0; n < 8; n++) op[n*16] = f2bf(v[n]);
    }
  }
}

// ---------------------------------------------------------------------------
// Fused q/k/v projections: X staged ONCE, 3 weight matrices streamed through
// one wt_s buffer; W DMA for y+1 overlaps the epilogue of y.
__global__ __launch_bounds__(256) void qkv_fused(
    const u16* __restrict__ X, const u16* __restrict__ WTd,
    const float* __restrict__ bq, const float* __restrict__ bk,
    const float* __restrict__ bv,
    u16* __restrict__ qb, u16* __restrict__ kb, u16* __restrict__ vb)
{
  __shared__ u16 wt_s[128*128];
  __shared__ u16 xs[128*128];
  const int t = threadIdx.x;
  const int lane = t & 63, w = t >> 6;
  const int l4 = lane >> 4, l15 = lane & 15;
  const long row0 = (long)blockIdx.x * 128;
  const int rr = lane >> 4;
  const int cb = (lane & 15) * 16;

  const char* xp = (const char*)(X + row0*HH);
  #pragma unroll
  for (int i = 0; i < 8; i++) {
    const int seg = w*8 + i;
    const int row = seg*4 + rr;
    gld_lds16(xp + (size_t)row*256 + (cb ^ ((row & 7) << 4)),
              (char*)xs + seg*1024);
  }
  #pragma unroll
  for (int i = 0; i < 8; i++) {
    const int seg = w*8 + i;
    const int row = seg*4 + rr;
    gld_lds16((const char*)WTd + (size_t)row*256 + (cb ^ ((row & 7) << 4)),
              (char*)wt_s + seg*1024);
  }
  __syncthreads();

  // hoist X fragments (constant across the 3 projections)
  bf16x8 af[2][4];
  #pragma unroll
  for (int m = 0; m < 2; m++)
    #pragma unroll
    for (int ks = 0; ks < 4; ks++)
      af[m][ks] = *(const bf16x8*)((const char*)xs + wswz(w*32 + m*16 + l15, ks*64 + l4*16));

  u16* const outs[3] = {qb, kb, vb};
  const float* const biases[3] = {bq, bk, bv};

  #pragma unroll
  for (int y = 0; y < 3; y++) {
    f32x4 acc[2][8];
    #pragma unroll
    for (int m = 0; m < 2; m++)
      #pragma unroll
      for (int n = 0; n < 8; n++)
        { acc[m][n][0]=0.f; acc[m][n][1]=0.f; acc[m][n][2]=0.f; acc[m][n][3]=0.f; }

    #pragma unroll
    for (int ks = 0; ks < 4; ks++) {
      bf16x8 bf[8];
      #pragma unroll
      for (int n = 0; n < 8; n++)
        bf[n] = *(const bf16x8*)((const char*)wt_s + wswz(n*16 + l15, ks*64 + l4*16));
      #pragma unroll
      for (int m = 0; m < 2; m++)
        #pragma unroll
        for (int n = 0; n < 8; n++)
          acc[m][n] = __builtin_amdgcn_mfma_f32_16x16x32_bf16(af[m][ks], bf[n], acc[m][n], 0, 0, 0);
    }
    __syncthreads();   // all waves done reading wt_s

    if (y < 2) {       // stream next W under the epilogue
      const char* wp = (const char*)(WTd + (size_t)(y+1)*HH*HH);
      #pragma unroll
      for (int i = 0; i < 8; i++) {
        const int seg = w*8 + i;
        const int row = seg*4 + rr;
        gld_lds16(wp + (size_t)row*256 + (cb ^ ((row & 7) << 4)),
                  (char*)wt_s + seg*1024);
      }
      __builtin_amdgcn_sched_barrier(0);
    }

    const float* bias = biases[y];
    u16* OUT = outs[y];
    float bia[8];
    #pragma unroll
    for (int n = 0; n < 8; n++) bia[n] = bias[n*16 + l15];
    #pragma unroll
    for (int m = 0; m < 2; m++) {
      #pragma unroll
      for (int r = 0; r < 4; r++) {
        const long row = row0 + w*32 + m*16 + l4*4 + r;
        u16* op = OUT + row*HH + l15;
        #pragma unroll
        for (int n = 0; n < 8; n++) op[n*16] = f2bf(acc[m][n][r] + bia[n]);
      }
    }

    if (y < 2) {
      asm volatile("s_waitcnt vmcnt(0)" ::: "memory");
      __builtin_amdgcn_s_barrier();
    }
  }
}

// ---------------------------------------------------------------------------
// v[B*N][128] bf16  ->  vT[(b*2+head)*64 + dh][512] bf16
__global__ __launch_bounds__(256) void transpose_v_kernel(
    const u16* __restrict__ vb, u16* __restrict__ vT)
{
  __shared__ u16 tile[128*128];
  const int t  = threadIdx.x;
  const int b  = blockIdx.x >> 2;
  const int n0 = (blockIdx.x & 3) * 128;

  #pragma unroll
  for (int i = 0; i < 8; i++) {
    const int chunk = t + 256*i;
    const int n = chunk >> 4, cslot = chunk & 15;
    uint4 d = *(const uint4*)(vb + ((size_t)(b*NN + n0 + n))*HH + cslot*8);
    *(uint4*)&tile[n*128 + ((cslot ^ ((n>>3)&7)) << 3)] = d;
  }
  __syncthreads();
  #pragma unroll
  for (int i = 0; i < 8; i++) {
    const int chunk = t + 256*i;
    const int c = chunk >> 4, nb = (chunk & 15) * 8;
    union { u16 s[8]; uint4 v; } u;
    #pragma unroll
    for (int j = 0; j < 8; j++) {
      const int n = nb + j;
      u.s[j] = tile[n*128 + ((((c>>3) ^ ((n>>3)&7)) << 3) | (c & 7))];
    }
    u16* op = vT + (((size_t)(b*2 + (c>>6)))*64 + (c & 63))*NN + n0 + nb;
    *(uint4*)op = u.v;
  }
}

// ---------------------------------------------------------------------------
// Flash attention, swapped 32x32 MFMA, P in registers.
// NEW: triple-buffered K/V with counted vmcnt (prefetch 2 ahead, never drain
// to 0 mid-loop) + XCD-bijective bid remap (4 q-tiles of one (b,head) land on
// the same XCD, adjacent in dispatch -> K/V re-reads are L2 hits).
__global__ __launch_bounds__(256) void attn_kernel(
    const u16* __restrict__ Q, const u16* __restrict__ K,
    const u16* __restrict__ VT, const int* __restrict__ lengths,
    u16* __restrict__ CTX)
{
  __shared__ u16 sh_q[128*64];     // 16KB
  __shared__ u16 sh_k[3][64*64];   // 24KB
  __shared__ u16 sh_v[3][64*64];   // 24KB
  const int t    = threadIdx.x;
  const int lane = t & 63;
  const int w    = t >> 6;
  // XCD remap: bid%8 = XCD (HW round-robin). qt from (bid>>3)&3, (b,head)
  // from {xcd, bid>>5} -> the 4 q-tile blocks of one (b,head) are bids
  // {x, x+8, x+16, x+24}: same XCD, adjacent in dispatch order.
  const int bid  = blockIdx.x;
  const int xcd  = bid & 7;
  const int idx  = bid >> 3;
  const int qt   = idx & 3;
  const int bh   = xcd + ((idx >> 2) << 3);   // 0..511, bijective
  const int head = bh & 1;
  const int b    = bh >> 1;
  const int L    = lengths[b];
  const int q0   = qt * 128;
  const int l31  = lane & 31;
  const int hi   = lane >> 5;
  const int rr8  = lane >> 3;          // DMA: row-in-seg (8 rows x 128B per 1KB seg)
  const int cb8  = (lane & 7) * 16;

  const char* qbase  = (const char*)(Q + ((size_t)(b*NN + q0))*HH + head*64);
  const char* kbase0 = (const char*)(K + ((size_t)(b*NN))*HH + head*64);
  const char* vbase0 = (const char*)(VT + (((size_t)(b*2 + head))*64)*NN);

  const bool q_allv   = (q0 + w*32 + 31) < L;   // wave-uniform
  const bool q_allinv = (q0 + w*32) >= L;       // wave-uniform
  const bool qv       = (q0 + w*32 + l31) < L;  // per-lane
  const int  nch      = (q0 + 127 < L) ? ((L + 63) >> 6) : 8;  // block-uniform

  // ---- prologue: DMA Q (4/lane) + chunk0 (4/lane) + chunk1 (4/lane) ----
  #pragma unroll
  for (int i = 0; i < 4; i++) {
    const int seg = w*4 + i;
    const int row = seg*8 + rr8;
    gld_lds16(qbase + (size_t)row*256 + (cb8 ^ ((row&7)<<4)),
              (char*)sh_q + seg*1024);
  }
  #pragma unroll
  for (int i = 0; i < 2; i++) {
    const int seg = w*2 + i;
    const int row = seg*8 + rr8;
    const int sw = cb8 ^ ((row&7)<<4);
    gld_lds16(kbase0 + (size_t)row*256  + sw, (char*)sh_k[0] + seg*1024);
    gld_lds16(vbase0 + (size_t)row*1024 + sw, (char*)sh_v[0] + seg*1024);
  }
  if (nch > 1) {
    const char* kb_ = kbase0 + (size_t)64*256;
    const char* vb_ = vbase0 + (size_t)128;
    #pragma unroll
    for (int i = 0; i < 2; i++) {
      const int seg = w*2 + i;
      const int row = seg*8 + rr8;
      const int sw = cb8 ^ ((row&7)<<4);
      gld_lds16(kb_ + (size_t)row*256  + sw, (char*)sh_k[1] + seg*1024);
      gld_lds16(vb_ + (size_t)row*1024 + sw, (char*)sh_v[1] + seg*1024);
    }
    asm volatile("s_waitcnt vmcnt(4)" ::: "memory");   // Q + chunk0 landed
  } else {
    asm volatile("s_waitcnt vmcnt(0)" ::: "memory");
  }
  __builtin_amdgcn_s_barrier();

  // Q fragments (B-operand): lane holds Q[q=l31][dh=16*st + 8*hi + j]
  bf16x8 qf[4];
  #pragma unroll
  for (int st = 0; st < 4; st++)
    qf[st] = *(const bf16x8*)((const char*)sh_q + kswz(w*32 + l31, st*32 + hi*16));

  f32x16 cacc[2];   // ctx^T accumulators (dh blocks 0-31, 32-63)
  #pragma unroll
  for (int r = 0; r < 16; r++) { cacc[0][r] = 0.f; cacc[1][r] = 0.f; }
  float l_run = 0.0f;

  int cur = 0;
  for (int ch = 0; ch < nch; ch++) {
    const bool more = (ch + 2 < nch);
    // prefetch chunk ch+2 into slot (cur+2)%3 (that buffer was last read at
    // chunk ch-1, released by the barrier that started this chunk)
    if (more) {
      const int s2 = (cur >= 1) ? cur - 1 : 2;   // (cur+2)%3
      const char* kb_ = kbase0 + (size_t)(ch+2)*64*256;
      const char* vb_ = vbase0 + (size_t)(ch+2)*128;
      #pragma unroll
      for (int i = 0; i < 2; i++) {
        const int seg = w*2 + i;
        const int row = seg*8 + rr8;
        const int sw = cb8 ^ ((row&7)<<4);
        gld_lds16(kb_ + (size_t)row*256  + sw, (char*)sh_k[s2] + seg*1024);
        gld_lds16(vb_ + (size_t)row*1024 + sw, (char*)sh_v[s2] + seg*1024);
      }
      __builtin_amdgcn_sched_barrier(0);   // pin issue point before compute
    }

    // fully-valid wave + fully-invalid chunk: P == 0, skip all compute
    const bool skip = q_allv && (ch*64 >= L);
    if (!skip) {
      // ---- S^T = K Q^T ----
      f32x16 sacc[2];
      #pragma unroll
      for (int r = 0; r < 16; r++) { sacc[0][r] = 0.f; sacc[1][r] = 0.f; }
      #pragma unroll
      for (int st = 0; st < 4; st++) {
        const bf16x8 kf0 = *(const bf16x8*)((const char*)sh_k[cur] + kswz(l31,      st*32 + hi*16));
        const bf16x8 kf1 = *(const bf16x8*)((const char*)sh_k[cur] + kswz(32 + l31, st*32 + hi*16));
        sacc[0] = __builtin_amdgcn_mfma_f32_32x32x16_bf16(kf0, qf[st], sacc[0], 0, 0, 0);
        sacc[1] = __builtin_amdgcn_mfma_f32_32x32x16_bf16(kf1, qf[st], sacc[1], 0, 0, 0);
      }

      // ---- softmax (lane-local rows) + pack P to bf16 words ----
      const bool fast = (ch*64 + 63 < L) || q_allinv;
      u32 pw[2][8];
      #pragma unroll
      for (int kb2 = 0; kb2 < 2; kb2++) {
        float p[16];
        float psum = 0.f;
        if (fast) {
          #pragma unroll
          for (int r = 0; r < 16; r++) {
            p[r] = exp2f(sacc[kb2][r] * QSCALE);
            psum += p[r];
          }
        } else {
          #pragma unroll
          for (int r = 0; r < 16; r++) {
            const int key = ch*64 + kb2*32 + (r&3) + 8*(r>>2) + 4*hi;
            const float bias = (qv && key >= L) ? NEGB : 0.0f;
            p[r] = exp2f(fmaf(sacc[kb2][r], QSCALE, bias));
            psum += p[r];
          }
        }
        l_run += psum;
        #pragma unroll
        for (int mm = 0; mm < 4; mm++)
          #pragma unroll
          for (int e = 0; e < 2; e++)
            pw[kb2][mm*2+e] = (u32)f2bf(p[4*mm+2*e]) | ((u32)f2bf(p[4*mm+2*e+1]) << 16);
      }

      // ---- PV: ctx^T += V^T P^T ----
      #pragma unroll
      for (int kb2 = 0; kb2 < 2; kb2++) {
        #pragma unroll
        for (int st = 0; st < 2; st++) {
          const u32 w00 = pw[kb2][(2*st+0)*2+0], w01 = pw[kb2][(2*st+0)*2+1];
          const u32 w10 = pw[kb2][(2*st+1)*2+0], w11 = pw[kb2][(2*st+1)*2+1];
          const u32 own0 = hi ? w10 : w00;
          const u32 own1 = hi ? w11 : w01;
          const u32 snd0 = hi ? w00 : w10;
          const u32 snd1 = hi ? w01 : w11;
          const u32 rcv0 = (u32)__shfl_xor((int)snd0, 32);
          const u32 rcv1 = (u32)__shfl_xor((int)snd1, 32);
          union { u32 u[4]; bf16x8 v; } pb;
          pb.u[0] = hi ? rcv0 : own0;
          pb.u[1] = hi ? rcv1 : own1;
          pb.u[2] = hi ? own0 : rcv0;
          pb.u[3] = hi ? own1 : rcv1;
          #pragma unroll
          for (int db = 0; db < 2; db++) {
            const bf16x8 vf = *(const bf16x8*)((const char*)sh_v[cur] +
                                kswz(db*32 + l31, kb2*64 + st*32 + hi*16));
            cacc[db] = __builtin_amdgcn_mfma_f32_32x32x16_bf16(vf, pb.v, cacc[db], 0, 0, 0);
          }
        }
      }
    }

    // end of chunk: wait chunk ch+1's loads (leave ch+2's in flight), barrier
    if (more) asm volatile("s_waitcnt vmcnt(4)" ::: "memory");
    else      asm volatile("s_waitcnt vmcnt(0)" ::: "memory");
    __builtin_amdgcn_s_barrier();
    cur = (cur == 2) ? 0 : cur + 1;
  }

  // ---- epilogue: full row-sum via one cross-half shuffle; lane-local write ----
  const float l_full = l_run + __shfl_xor(l_run, 32);
  const float inv = 1.0f / l_full;
  const int qrow = q0 + w*32 + l31;
  u16* crow = CTX + ((size_t)(b*NN) + qrow)*HH + head*64;
  #pragma unroll
  for (int db = 0; db < 2; db++)
    #pragma unroll
    for (int mm = 0; mm < 4; mm++) {
      const int dh0 = db*32 + mm*8 + hi*4;
      uint2 o;
      o.x = (u32)f2bf(cacc[db][4*mm+0]*inv) | ((u32)f2bf(cacc[db][4*mm+1]*inv) << 16);
      o.y = (u32)f2bf(cacc[db][4*mm+2]*inv) | ((u32)f2bf(cacc[db][4*mm+3]*inv) << 16);
      *(uint2*)(crow + dh0) = o;
    }
}

// ---------------------------------------------------------------------------
// h = LN(relu(ctx) + h); ctx bf16, h bf16 in/out. One wave per row.
__global__ __launch_bounds__(256) void resln_kernel(
    const u16* __restrict__ CTX, u16* Hb,
    const float* __restrict__ gl, const float* __restrict__ bl)
{
  const int t = threadIdx.x;
  const int lane = t & 63;
  const long row = (long)blockIdx.x*4 + (t >> 6);
  const u32 craw = *(const u32*)&CTX[row*HH + lane*2];
  const u32 hraw = *(const u32*)&Hb[row*HH + lane*2];
  const float c0 = bf2f((u16)(craw & 0xffff)), c1 = bf2f((u16)(craw >> 16));
  const float h0 = bf2f((u16)(hraw & 0xffff)), h1 = bf2f((u16)(hraw >> 16));
  const float x0 = fmaxf(c0, 0.0f) + h0;
  const float x1 = fmaxf(c1, 0.0f) + h1;
  float s = x0 + x1, ss = x0*x0 + x1*x1;
  #pragma unroll
  for (int off = 1; off < 64; off <<= 1) {
    s  += __shfl_xor(s,  off);
    ss += __shfl_xor(ss, off);
  }
  const float mean = s * (1.0f/128.0f);
  const float rstd = rsqrtf(ss*(1.0f/128.0f) - mean*mean + 1e-5f);
  const float o0 = (x0 - mean)*rstd*gl[lane*2]   + bl[lane*2];
  const float o1 = (x1 - mean)*rstd*gl[lane*2+1] + bl[lane*2+1];
  *(u32*)&Hb[row*HH + lane*2] = (u32)f2bf(o0) | ((u32)f2bf(o1) << 16);
}

// out[b, col] = max over n of h[b, n, col]; h bf16, out f32
__global__ __launch_bounds__(256) void maxred_kernel(
    const u16* __restrict__ Hb, float* __restrict__ out)
{
  __shared__ float red[256];
  const int b = blockIdx.x;
  const int col = threadIdx.x & 127, half = threadIdx.x >> 7;
  const u16* hp = Hb + ((size_t)b*NN + half*256)*HH + col;
  float m0 = -3.0e38f, m1 = -3.0e38f, m2 = -3.0e38f, m3 = -3.0e38f;
  for (int r = 0; r < 256; r += 4) {
    m0 = fmaxf(m0, bf2f(hp[(r+0)*HH]));
    m1 = fmaxf(m1, bf2f(hp[(r+1)*HH]));
    m2 = fmaxf(m2, bf2f(hp[(r+2)*HH]));
    m3 = fmaxf(m3, bf2f(hp[(r+3)*HH]));
  }
  red[threadIdx.x] = fmaxf(fmaxf(m0, m1), fmaxf(m2, m3));
  __syncthreads();
  if (half == 0) out[(size_t)b*HH + col] = fmaxf(red[col], red[col + 128]);
}

// ---------------------------------------------------------------------------
extern "C" void kernel_launch(void* const* d_in, const int* in_sizes, int n_in,
                              void* d_out, int out_size, void* d_ws, size_t ws_size,
                              hipStream_t stream)
{
  const float* x   = (const float*)d_in[0];
  const int* lens  = (const int*)d_in[1];
  const float* W0  = (const float*)d_in[2];
  const float* b0  = (const float*)d_in[3];
  const float* g0  = (const float*)d_in[4];
  const float* be0 = (const float*)d_in[5];
  const float* W1  = (const float*)d_in[6];
  const float* b1  = (const float*)d_in[7];
  const float* g1  = (const float*)d_in[8];
  const float* be1 = (const float*)d_in[9];
  const float* Wq  = (const float*)d_in[10];
  const float* bq  = (const float*)d_in[11];
  const float* Wk  = (const float*)d_in[12];
  const float* bk  = (const float*)d_in[13];
  const float* Wv  = (const float*)d_in[14];
  const float* bv  = (const float*)d_in[15];
  const float* gl  = (const float*)d_in[16];
  const float* bl  = (const float*)d_in[17];
  float* out = (float*)d_out;

  u16* h    = (u16*)d_ws;                  // 32MB
  u16* ctxb = h    + (size_t)MM*HH;        // 32MB
  u16* qb   = ctxb + (size_t)MM*HH;        // 32MB
  u16* kb   = qb   + (size_t)MM*HH;        // 32MB
  u16* vb   = kb   + (size_t)MM*HH;        // 32MB
  u16* vT   = vb   + (size_t)MM*HH;        // 32MB
  u16* wt   = vT   + (size_t)MM*HH;        // 352KB (11 x 128 x 128 bf16)

  wt_prep<<<11, 256, 0, stream>>>(W0, W1, Wq, Wk, Wv, wt);

  linear_mfma<true ,true ><<<MM/128, 256, 0, stream>>>(x, wt,           b0, g0, be0, h);
  linear_mfma<false,true ><<<MM/128, 256, 0, stream>>>(h, wt + 1*HH*HH, b1, g1, be1, h);

  for (int d = 0; d < 3; d++) {
    qkv_fused<<<MM/128, 256, 0, stream>>>(
        h, wt + (2+3*d)*HH*HH, bq + d*HH, bk + d*HH, bv + d*HH, qb, kb, vb);
    transpose_v_kernel<<<BB*4, 256, 0, stream>>>(vb, vT);
    attn_kernel<<<BB*2*4, 256, 0, stream>>>(qb, kb, vT, lens, ctxb);
    resln_kernel<<<MM/4, 256, 0, stream>>>(ctxb, h, gl + d*HH, bl + d*HH);
  }
  maxred_kernel<<<BB, 256, 0, stream>>>(h, out);
}

// Round 10
// 565.313 us; speedup vs baseline: 1.0608x; 1.0608x over previous
//
#include <hip/hip_runtime.h>
#include <hip/hip_bf16.h>

#define BB 256
#define NN 512
#define HH 128
#define MM (BB*NN)

typedef unsigned short u16;
typedef unsigned int   u32;
typedef __attribute__((ext_vector_type(8))) short bf16x8;   // 8 bf16 (4 VGPRs)
typedef __attribute__((ext_vector_type(4))) float f32x4;
typedef __attribute__((ext_vector_type(16))) float f32x16;

#define LOG2E  1.4426950408889634f
#define QSCALE (0.125f * LOG2E)       // 1/sqrt(64) folded with log2(e) for exp2
#define NEGB   (-10000.0f * LOG2E)    // mask bias in log2 domain -> exp2 underflows to 0

// byte offset of (row, cbyte) in a [*][64]bf16 (128B-row) LDS tile, XOR-swizzled
__device__ __forceinline__ int kswz(int row, int cbyte) {
  return row*128 + (cbyte ^ ((row & 7) << 4));
}
// same for [*][128]bf16 (256B-row) tiles
__device__ __forceinline__ int wswz(int row, int cbyte) {
  return row*256 + (cbyte ^ ((row & 7) << 4));
}

__device__ __forceinline__ u16 f2bf(float x) {   // f32 -> bf16 RNE
  __hip_bfloat16 h = __float2bfloat16(x);
  return *reinterpret_cast<u16*>(&h);
}
__device__ __forceinline__ float bf2f(u16 x) {
  return __uint_as_float(((u32)x) << 16);
}

// async global->LDS DMA, 16B per lane; LDS dest = wave-uniform base + lane*16.
__device__ __forceinline__ void gld_lds16(const void* g, void* l) {
  __builtin_amdgcn_global_load_lds(
      (__attribute__((address_space(1))) const unsigned int*)g,
      (__attribute__((address_space(3))) unsigned int*)l, 16, 0, 0);
}

// ---------------------------------------------------------------------------
// Pre-transpose + bf16-convert the 11 weight matrices: wt[i] = W_i^T [c][k]
__global__ __launch_bounds__(256) void wt_prep(
    const float* __restrict__ W0, const float* __restrict__ W1,
    const float* __restrict__ Wq, const float* __restrict__ Wk,
    const float* __restrict__ Wv, u16* __restrict__ wt)
{
  __shared__ u16 tile[128*128];
  const int t = threadIdx.x;
  const int i = blockIdx.x;
  const float* src;
  if (i == 0) src = W0;
  else if (i == 1) src = W1;
  else {
    const int d = (i-2)/3, which = (i-2)%3;
    src = (which==0 ? Wq : which==1 ? Wk : Wv) + d*HH*HH;
  }
  u16* dst = wt + (size_t)i*HH*HH;

  #pragma unroll
  for (int j = 0; j < 8; j++) {
    const int chunk = t + 256*j;
    const int k = chunk >> 4, c8 = (chunk & 15)*8;
    const float4 a = *(const float4*)&src[k*HH + c8];
    const float4 b = *(const float4*)&src[k*HH + c8 + 4];
    union { u16 s[8]; uint4 v; } u;
    u.s[0]=f2bf(a.x); u.s[1]=f2bf(a.y); u.s[2]=f2bf(a.z); u.s[3]=f2bf(a.w);
    u.s[4]=f2bf(b.x); u.s[5]=f2bf(b.y); u.s[6]=f2bf(b.z); u.s[7]=f2bf(b.w);
    *(uint4*)&tile[k*128 + (((chunk & 15) ^ ((k>>3)&7)) << 3)] = u.v;
  }
  __syncthreads();
  #pragma unroll
  for (int j = 0; j < 8; j++) {
    const int chunk = t + 256*j;
    const int c = chunk >> 4, kb8 = (chunk & 15)*8;
    union { u16 s[8]; uint4 v; } u;
    #pragma unroll
    for (int e = 0; e < 8; e++) {
      const int k = kb8 + e;
      u.s[e] = tile[k*128 + ((((c>>3) ^ ((k>>3)&7)) << 3) | (c & 7))];
    }
    *(uint4*)&dst[c*HH + kb8] = u.v;
  }
}

// ---------------------------------------------------------------------------
// MLP linears (2 uses): OUT[M,128](bf16) = LNRELU ? relu(LN(X@W+b)) : X@W+b
template<bool F32IN, bool LNRELU>
__global__ __launch_bounds__(256) void linear_mfma(
    const void* __restrict__ Xv, const u16* __restrict__ WT,
    const float* __restrict__ bias, const float* __restrict__ gamma,
    const float* __restrict__ beta, u16* __restrict__ OUT)
{
  __shared__ u16 wt_s[128*128];  // W^T tile, swizzled 32KB
  __shared__ u16 xs[128*128];    // X tile,   swizzled 32KB
  const int t = threadIdx.x;
  const int lane = t & 63, w = t >> 6;
  const int l4 = lane >> 4, l15 = lane & 15;
  const long row0 = (long)blockIdx.x * 128;

  {
    const int rr = lane >> 4;
    const int cb = (lane & 15) * 16;
    #pragma unroll
    for (int i = 0; i < 8; i++) {
      const int seg = w*8 + i;
      const int row = seg*4 + rr;
      gld_lds16((const char*)WT + (size_t)row*256 + (cb ^ ((row & 7) << 4)),
                (char*)wt_s + seg*1024);
    }
    if constexpr (!F32IN) {
      const char* xp = (const char*)((const u16*)Xv + row0*HH);
      #pragma unroll
      for (int i = 0; i < 8; i++) {
        const int seg = w*8 + i;
        const int row = seg*4 + rr;
        gld_lds16(xp + (size_t)row*256 + (cb ^ ((row & 7) << 4)),
                  (char*)xs + seg*1024);
      }
    }
  }
  if constexpr (F32IN) {
    const float* xp = (const float*)Xv + row0*HH;
    #pragma unroll
    for (int i = 0; i < 8; i++) {
      const int chunk = t + 256*i;
      const int r = chunk >> 4, c8 = (chunk & 15)*8;
      const float4 a = *(const float4*)&xp[r*HH + c8];
      const float4 b = *(const float4*)&xp[r*HH + c8 + 4];
      union { u16 s[8]; uint4 v; } u;
      u.s[0]=f2bf(a.x); u.s[1]=f2bf(a.y); u.s[2]=f2bf(a.z); u.s[3]=f2bf(a.w);
      u.s[4]=f2bf(b.x); u.s[5]=f2bf(b.y); u.s[6]=f2bf(b.z); u.s[7]=f2bf(b.w);
      *(uint4*)((char*)xs + wswz(r, c8*2)) = u.v;
    }
  }
  __syncthreads();

  f32x4 acc[2][8];
  #pragma unroll
  for (int m = 0; m < 2; m++)
    #pragma unroll
    for (int n = 0; n < 8; n++)
      { acc[m][n][0]=0.f; acc[m][n][1]=0.f; acc[m][n][2]=0.f; acc[m][n][3]=0.f; }

  #pragma unroll
  for (int ks = 0; ks < 4; ks++) {
    bf16x8 af[2], bf[8];
    #pragma unroll
    for (int m = 0; m < 2; m++)
      af[m] = *(const bf16x8*)((const char*)xs + wswz(w*32 + m*16 + l15, ks*64 + l4*16));
    #pragma unroll
    for (int n = 0; n < 8; n++)
      bf[n] = *(const bf16x8*)((const char*)wt_s + wswz(n*16 + l15, ks*64 + l4*16));
    #pragma unroll
    for (int m = 0; m < 2; m++)
      #pragma unroll
      for (int n = 0; n < 8; n++)
        acc[m][n] = __builtin_amdgcn_mfma_f32_16x16x32_bf16(af[m], bf[n], acc[m][n], 0, 0, 0);
  }

  float bia[8], gam[8], bet[8];
  #pragma unroll
  for (int n = 0; n < 8; n++) {
    bia[n] = bias[n*16 + l15];
    if constexpr (LNRELU) { gam[n] = gamma[n*16 + l15]; bet[n] = beta[n*16 + l15]; }
  }
  #pragma unroll
  for (int m = 0; m < 2; m++) {
    #pragma unroll
    for (int r = 0; r < 4; r++) {
      const long row = row0 + w*32 + m*16 + l4*4 + r;
      float v[8];
      #pragma unroll
      for (int n = 0; n < 8; n++) v[n] = acc[m][n][r] + bia[n];
      if constexpr (LNRELU) {
        float s = 0.f, ss = 0.f;
        #pragma unroll
        for (int n = 0; n < 8; n++) { s += v[n]; ss += v[n]*v[n]; }
        #pragma unroll
        for (int off = 1; off < 16; off <<= 1) {
          s  += __shfl_xor(s,  off);
          ss += __shfl_xor(ss, off);
        }
        const float mean = s * (1.0f/128.0f);
        const float rstd = rsqrtf(ss*(1.0f/128.0f) - mean*mean + 1e-5f);
        #pragma unroll
        for (int n = 0; n < 8; n++)
          v[n] = fmaxf((v[n] - mean)*rstd*gam[n] + bet[n], 0.0f);
      }
      u16* op = OUT + row*HH + l15;
      #pragma unroll
      for (int n = 0; n < 8; n++) op[n*16] = f2bf(v[n]);
    }
  }
}

// ---------------------------------------------------------------------------
// Fused q/k/v projections: X staged ONCE, 3 weight matrices streamed through
// one wt_s buffer; W DMA for y+1 overlaps the epilogue of y.
__global__ __launch_bounds__(256) void qkv_fused(
    const u16* __restrict__ X, const u16* __restrict__ WTd,
    const float* __restrict__ bq, const float* __restrict__ bk,
    const float* __restrict__ bv,
    u16* __restrict__ qb, u16* __restrict__ kb, u16* __restrict__ vb)
{
  __shared__ u16 wt_s[128*128];
  __shared__ u16 xs[128*128];
  const int t = threadIdx.x;
  const int lane = t & 63, w = t >> 6;
  const int l4 = lane >> 4, l15 = lane & 15;
  const long row0 = (long)blockIdx.x * 128;
  const int rr = lane >> 4;
  const int cb = (lane & 15) * 16;

  const char* xp = (const char*)(X + row0*HH);
  #pragma unroll
  for (int i = 0; i < 8; i++) {
    const int seg = w*8 + i;
    const int row = seg*4 + rr;
    gld_lds16(xp + (size_t)row*256 + (cb ^ ((row & 7) << 4)),
              (char*)xs + seg*1024);
  }
  #pragma unroll
  for (int i = 0; i < 8; i++) {
    const int seg = w*8 + i;
    const int row = seg*4 + rr;
    gld_lds16((const char*)WTd + (size_t)row*256 + (cb ^ ((row & 7) << 4)),
              (char*)wt_s + seg*1024);
  }
  __syncthreads();

  // hoist X fragments (constant across the 3 projections)
  bf16x8 af[2][4];
  #pragma unroll
  for (int m = 0; m < 2; m++)
    #pragma unroll
    for (int ks = 0; ks < 4; ks++)
      af[m][ks] = *(const bf16x8*)((const char*)xs + wswz(w*32 + m*16 + l15, ks*64 + l4*16));

  u16* const outs[3] = {qb, kb, vb};
  const float* const biases[3] = {bq, bk, bv};

  #pragma unroll
  for (int y = 0; y < 3; y++) {
    f32x4 acc[2][8];
    #pragma unroll
    for (int m = 0; m < 2; m++)
      #pragma unroll
      for (int n = 0; n < 8; n++)
        { acc[m][n][0]=0.f; acc[m][n][1]=0.f; acc[m][n][2]=0.f; acc[m][n][3]=0.f; }

    #pragma unroll
    for (int ks = 0; ks < 4; ks++) {
      bf16x8 bf[8];
      #pragma unroll
      for (int n = 0; n < 8; n++)
        bf[n] = *(const bf16x8*)((const char*)wt_s + wswz(n*16 + l15, ks*64 + l4*16));
      #pragma unroll
      for (int m = 0; m < 2; m++)
        #pragma unroll
        for (int n = 0; n < 8; n++)
          acc[m][n] = __builtin_amdgcn_mfma_f32_16x16x32_bf16(af[m][ks], bf[n], acc[m][n], 0, 0, 0);
    }
    __syncthreads();   // all waves done reading wt_s

    if (y < 2) {       // stream next W under the epilogue
      const char* wp = (const char*)(WTd + (size_t)(y+1)*HH*HH);
      #pragma unroll
      for (int i = 0; i < 8; i++) {
        const int seg = w*8 + i;
        const int row = seg*4 + rr;
        gld_lds16(wp + (size_t)row*256 + (cb ^ ((row & 7) << 4)),
                  (char*)wt_s + seg*1024);
      }
      __builtin_amdgcn_sched_barrier(0);
    }

    const float* bias = biases[y];
    u16* OUT = outs[y];
    float bia[8];
    #pragma unroll
    for (int n = 0; n < 8; n++) bia[n] = bias[n*16 + l15];
    #pragma unroll
    for (int m = 0; m < 2; m++) {
      #pragma unroll
      for (int r = 0; r < 4; r++) {
        const long row = row0 + w*32 + m*16 + l4*4 + r;
        u16* op = OUT + row*HH + l15;
        #pragma unroll
        for (int n = 0; n < 8; n++) op[n*16] = f2bf(acc[m][n][r] + bia[n]);
      }
    }

    if (y < 2) {
      asm volatile("s_waitcnt vmcnt(0)" ::: "memory");
      __builtin_amdgcn_s_barrier();
    }
  }
}

// ---------------------------------------------------------------------------
// v[B*N][128] bf16  ->  vT[(b*2+head)*64 + dh][512] bf16
__global__ __launch_bounds__(256) void transpose_v_kernel(
    const u16* __restrict__ vb, u16* __restrict__ vT)
{
  __shared__ u16 tile[128*128];
  const int t  = threadIdx.x;
  const int b  = blockIdx.x >> 2;
  const int n0 = (blockIdx.x & 3) * 128;

  #pragma unroll
  for (int i = 0; i < 8; i++) {
    const int chunk = t + 256*i;
    const int n = chunk >> 4, cslot = chunk & 15;
    uint4 d = *(const uint4*)(vb + ((size_t)(b*NN + n0 + n))*HH + cslot*8);
    *(uint4*)&tile[n*128 + ((cslot ^ ((n>>3)&7)) << 3)] = d;
  }
  __syncthreads();
  #pragma unroll
  for (int i = 0; i < 8; i++) {
    const int chunk = t + 256*i;
    const int c = chunk >> 4, nb = (chunk & 15) * 8;
    union { u16 s[8]; uint4 v; } u;
    #pragma unroll
    for (int j = 0; j < 8; j++) {
      const int n = nb + j;
      u.s[j] = tile[n*128 + ((((c>>3) ^ ((n>>3)&7)) << 3) | (c & 7))];
    }
    u16* op = vT + (((size_t)(b*2 + (c>>6)))*64 + (c & 63))*NN + n0 + nb;
    *(uint4*)op = u.v;
  }
}

// ---------------------------------------------------------------------------
// Flash attention, swapped 32x32 MFMA, P in registers.
// Triple-buffered K/V with counted vmcnt; slot 2 OVERLAYS the Q staging
// buffer (Q lives in registers after the prologue) -> 48KB LDS, 3 blocks/CU.
// XCD-bijective bid remap: 4 q-tiles of one (b,head) on the same XCD.
__global__ __launch_bounds__(256) void attn_kernel(
    const u16* __restrict__ Q, const u16* __restrict__ K,
    const u16* __restrict__ VT, const int* __restrict__ lengths,
    u16* __restrict__ CTX)
{
  __shared__ u16 sh_k01[2][64*64];   // 16KB: K slots 0,1
  __shared__ u16 sh_v01[2][64*64];   // 16KB: V slots 0,1
  __shared__ u16 sh_q2[128*64];      // 16KB: Q staging, then K/V slot 2
  u16* const k2 = sh_q2;             // 8KB
  u16* const v2 = sh_q2 + 64*64;     // 8KB
  const int t    = threadIdx.x;
  const int lane = t & 63;
  const int w    = t >> 6;
  const int bid  = blockIdx.x;
  const int xcd  = bid & 7;
  const int idx  = bid >> 3;
  const int qt   = idx & 3;
  const int bh   = xcd + ((idx >> 2) << 3);   // 0..511, bijective
  const int head = bh & 1;
  const int b    = bh >> 1;
  const int L    = lengths[b];
  const int q0   = qt * 128;
  const int l31  = lane & 31;
  const int hi   = lane >> 5;
  const int rr8  = lane >> 3;          // DMA: row-in-seg (8 rows x 128B per 1KB seg)
  const int cb8  = (lane & 7) * 16;

  const char* qbase  = (const char*)(Q + ((size_t)(b*NN + q0))*HH + head*64);
  const char* kbase0 = (const char*)(K + ((size_t)(b*NN))*HH + head*64);
  const char* vbase0 = (const char*)(VT + (((size_t)(b*2 + head))*64)*NN);

  const bool q_allv   = (q0 + w*32 + 31) < L;   // wave-uniform
  const bool q_allinv = (q0 + w*32) >= L;       // wave-uniform
  const bool qv       = (q0 + w*32 + l31) < L;  // per-lane
  const int  nch      = (q0 + 127 < L) ? ((L + 63) >> 6) : 8;  // block-uniform

  // ---- prologue: DMA Q (4/lane) + chunk0 (4/lane) + chunk1 (4/lane) ----
  #pragma unroll
  for (int i = 0; i < 4; i++) {
    const int seg = w*4 + i;
    const int row = seg*8 + rr8;
    gld_lds16(qbase + (size_t)row*256 + (cb8 ^ ((row&7)<<4)),
              (char*)sh_q2 + seg*1024);
  }
  #pragma unroll
  for (int i = 0; i < 2; i++) {
    const int seg = w*2 + i;
    const int row = seg*8 + rr8;
    const int sw = cb8 ^ ((row&7)<<4);
    gld_lds16(kbase0 + (size_t)row*256  + sw, (char*)sh_k01[0] + seg*1024);
    gld_lds16(vbase0 + (size_t)row*1024 + sw, (char*)sh_v01[0] + seg*1024);
  }
  if (nch > 1) {
    const char* kb_ = kbase0 + (size_t)64*256;
    const char* vb_ = vbase0 + (size_t)128;
    #pragma unroll
    for (int i = 0; i < 2; i++) {
      const int seg = w*2 + i;
      const int row = seg*8 + rr8;
      const int sw = cb8 ^ ((row&7)<<4);
      gld_lds16(kb_ + (size_t)row*256  + sw, (char*)sh_k01[1] + seg*1024);
      gld_lds16(vb_ + (size_t)row*1024 + sw, (char*)sh_v01[1] + seg*1024);
    }
    asm volatile("s_waitcnt vmcnt(4)" ::: "memory");   // Q + chunk0 landed
  } else {
    asm volatile("s_waitcnt vmcnt(0)" ::: "memory");
  }
  __builtin_amdgcn_s_barrier();

  // Q fragments (B-operand): lane holds Q[q=l31][dh=16*st + 8*hi + j].
  // Must fully complete before any wave DMAs slot 2 over this region.
  bf16x8 qf[4];
  #pragma unroll
  for (int st = 0; st < 4; st++)
    qf[st] = *(const bf16x8*)((const char*)sh_q2 + kswz(w*32 + l31, st*32 + hi*16));
  asm volatile("s_waitcnt lgkmcnt(0)" ::: "memory");
  __builtin_amdgcn_sched_barrier(0);
  __builtin_amdgcn_s_barrier();      // all waves' Q reads landed in VGPRs

  f32x16 cacc[2];   // ctx^T accumulators (dh blocks 0-31, 32-63)
  #pragma unroll
  for (int r = 0; r < 16; r++) { cacc[0][r] = 0.f; cacc[1][r] = 0.f; }
  float l_run = 0.0f;

  int cur = 0;
  for (int ch = 0; ch < nch; ch++) {
    const bool more = (ch + 2 < nch);
    const u16* kc = (cur == 0) ? sh_k01[0] : (cur == 1) ? sh_k01[1] : k2;
    const u16* vc = (cur == 0) ? sh_v01[0] : (cur == 1) ? sh_v01[1] : v2;
    // prefetch chunk ch+2 into slot (cur+2)%3 (released by this chunk's
    // opening barrier: last read at chunk ch-1)
    if (more) {
      const int s2 = (cur >= 1) ? cur - 1 : 2;   // (cur+2)%3
      u16* kd = (s2 == 0) ? sh_k01[0] : (s2 == 1) ? sh_k01[1] : k2;
      u16* vd = (s2 == 0) ? sh_v01[0] : (s2 == 1) ? sh_v01[1] : v2;
      const char* kb_ = kbase0 + (size_t)(ch+2)*64*256;
      const char* vb_ = vbase0 + (size_t)(ch+2)*128;
      #pragma unroll
      for (int i = 0; i < 2; i++) {
        const int seg = w*2 + i;
        const int row = seg*8 + rr8;
        const int sw = cb8 ^ ((row&7)<<4);
        gld_lds16(kb_ + (size_t)row*256  + sw, (char*)kd + seg*1024);
        gld_lds16(vb_ + (size_t)row*1024 + sw, (char*)vd + seg*1024);
      }
      __builtin_amdgcn_sched_barrier(0);   // pin issue point before compute
    }

    // fully-valid wave + fully-invalid chunk: P == 0, skip all compute
    const bool skip = q_allv && (ch*64 >= L);
    if (!skip) {
      // ---- S^T = K Q^T ----
      f32x16 sacc[2];
      #pragma unroll
      for (int r = 0; r < 16; r++) { sacc[0][r] = 0.f; sacc[1][r] = 0.f; }
      #pragma unroll
      for (int st = 0; st < 4; st++) {
        const bf16x8 kf0 = *(const bf16x8*)((const char*)kc + kswz(l31,      st*32 + hi*16));
        const bf16x8 kf1 = *(const bf16x8*)((const char*)kc + kswz(32 + l31, st*32 + hi*16));
        sacc[0] = __builtin_amdgcn_mfma_f32_32x32x16_bf16(kf0, qf[st], sacc[0], 0, 0, 0);
        sacc[1] = __builtin_amdgcn_mfma_f32_32x32x16_bf16(kf1, qf[st], sacc[1], 0, 0, 0);
      }

      // ---- softmax (lane-local rows) + pack P to bf16 words ----
      const bool fast = (ch*64 + 63 < L) || q_allinv;
      u32 pw[2][8];
      #pragma unroll
      for (int kb2 = 0; kb2 < 2; kb2++) {
        float p[16];
        float psum = 0.f;
        if (fast) {
          #pragma unroll
          for (int r = 0; r < 16; r++) {
            p[r] = exp2f(sacc[kb2][r] * QSCALE);
            psum += p[r];
          }
        } else {
          #pragma unroll
          for (int r = 0; r < 16; r++) {
            const int key = ch*64 + kb2*32 + (r&3) + 8*(r>>2) + 4*hi;
            const float bias = (qv && key >= L) ? NEGB : 0.0f;
            p[r] = exp2f(fmaf(sacc[kb2][r], QSCALE, bias));
            psum += p[r];
          }
        }
        l_run += psum;
        #pragma unroll
        for (int mm = 0; mm < 4; mm++)
          #pragma unroll
          for (int e = 0; e < 2; e++)
            pw[kb2][mm*2+e] = (u32)f2bf(p[4*mm+2*e]) | ((u32)f2bf(p[4*mm+2*e+1]) << 16);
      }

      // ---- PV: ctx^T += V^T P^T ----
      #pragma unroll
      for (int kb2 = 0; kb2 < 2; kb2++) {
        #pragma unroll
        for (int st = 0; st < 2; st++) {
          const u32 w00 = pw[kb2][(2*st+0)*2+0], w01 = pw[kb2][(2*st+0)*2+1];
          const u32 w10 = pw[kb2][(2*st+1)*2+0], w11 = pw[kb2][(2*st+1)*2+1];
          const u32 own0 = hi ? w10 : w00;
          const u32 own1 = hi ? w11 : w01;
          const u32 snd0 = hi ? w00 : w10;
          const u32 snd1 = hi ? w01 : w11;
          const u32 rcv0 = (u32)__shfl_xor((int)snd0, 32);
          const u32 rcv1 = (u32)__shfl_xor((int)snd1, 32);
          union { u32 u[4]; bf16x8 v; } pb;
          pb.u[0] = hi ? rcv0 : own0;
          pb.u[1] = hi ? rcv1 : own1;
          pb.u[2] = hi ? own0 : rcv0;
          pb.u[3] = hi ? own1 : rcv1;
          #pragma unroll
          for (int db = 0; db < 2; db++) {
            const bf16x8 vf = *(const bf16x8*)((const char*)vc +
                                kswz(db*32 + l31, kb2*64 + st*32 + hi*16));
            cacc[db] = __builtin_amdgcn_mfma_f32_32x32x16_bf16(vf, pb.v, cacc[db], 0, 0, 0);
          }
        }
      }
    }

    // end of chunk: wait chunk ch+1's loads (leave ch+2's in flight), barrier
    if (more) asm volatile("s_waitcnt vmcnt(4)" ::: "memory");
    else      asm volatile("s_waitcnt vmcnt(0)" ::: "memory");
    __builtin_amdgcn_s_barrier();
    cur = (cur == 2) ? 0 : cur + 1;
  }

  // ---- epilogue: full row-sum via one cross-half shuffle; lane-local write ----
  const float l_full = l_run + __shfl_xor(l_run, 32);
  const float inv = 1.0f / l_full;
  const int qrow = q0 + w*32 + l31;
  u16* crow = CTX + ((size_t)(b*NN) + qrow)*HH + head*64;
  #pragma unroll
  for (int db = 0; db < 2; db++)
    #pragma unroll
    for (int mm = 0; mm < 4; mm++) {
      const int dh0 = db*32 + mm*8 + hi*4;
      uint2 o;
      o.x = (u32)f2bf(cacc[db][4*mm+0]*inv) | ((u32)f2bf(cacc[db][4*mm+1]*inv) << 16);
      o.y = (u32)f2bf(cacc[db][4*mm+2]*inv) | ((u32)f2bf(cacc[db][4*mm+3]*inv) << 16);
      *(uint2*)(crow + dh0) = o;
    }
}

// ---------------------------------------------------------------------------
// h = LN(relu(ctx) + h); ctx bf16, h bf16 in/out. One wave per row.
__global__ __launch_bounds__(256) void resln_kernel(
    const u16* __restrict__ CTX, u16* Hb,
    const float* __restrict__ gl, const float* __restrict__ bl)
{
  const int t = threadIdx.x;
  const int lane = t & 63;
  const long row = (long)blockIdx.x*4 + (t >> 6);
  const u32 craw = *(const u32*)&CTX[row*HH + lane*2];
  const u32 hraw = *(const u32*)&Hb[row*HH + lane*2];
  const float c0 = bf2f((u16)(craw & 0xffff)), c1 = bf2f((u16)(craw >> 16));
  const float h0 = bf2f((u16)(hraw & 0xffff)), h1 = bf2f((u16)(hraw >> 16));
  const float x0 = fmaxf(c0, 0.0f) + h0;
  const float x1 = fmaxf(c1, 0.0f) + h1;
  float s = x0 + x1, ss = x0*x0 + x1*x1;
  #pragma unroll
  for (int off = 1; off < 64; off <<= 1) {
    s  += __shfl_xor(s,  off);
    ss += __shfl_xor(ss, off);
  }
  const float mean = s * (1.0f/128.0f);
  const float rstd = rsqrtf(ss*(1.0f/128.0f) - mean*mean + 1e-5f);
  const float o0 = (x0 - mean)*rstd*gl[lane*2]   + bl[lane*2];
  const float o1 = (x1 - mean)*rstd*gl[lane*2+1] + bl[lane*2+1];
  *(u32*)&Hb[row*HH + lane*2] = (u32)f2bf(o0) | ((u32)f2bf(o1) << 16);
}

// out[b, col] = max over n of h[b, n, col]; h bf16, out f32
__global__ __launch_bounds__(256) void maxred_kernel(
    const u16* __restrict__ Hb, float* __restrict__ out)
{
  __shared__ float red[256];
  const int b = blockIdx.x;
  const int col = threadIdx.x & 127, half = threadIdx.x >> 7;
  const u16* hp = Hb + ((size_t)b*NN + half*256)*HH + col;
  float m0 = -3.0e38f, m1 = -3.0e38f, m2 = -3.0e38f, m3 = -3.0e38f;
  for (int r = 0; r < 256; r += 4) {
    m0 = fmaxf(m0, bf2f(hp[(r+0)*HH]));
    m1 = fmaxf(m1, bf2f(hp[(r+1)*HH]));
    m2 = fmaxf(m2, bf2f(hp[(r+2)*HH]));
    m3 = fmaxf(m3, bf2f(hp[(r+3)*HH]));
  }
  red[threadIdx.x] = fmaxf(fmaxf(m0, m1), fmaxf(m2, m3));
  __syncthreads();
  if (half == 0) out[(size_t)b*HH + col] = fmaxf(red[col], red[col + 128]);
}

// ---------------------------------------------------------------------------
extern "C" void kernel_launch(void* const* d_in, const int* in_sizes, int n_in,
                              void* d_out, int out_size, void* d_ws, size_t ws_size,
                              hipStream_t stream)
{
  const float* x   = (const float*)d_in[0];
  const int* lens  = (const int*)d_in[1];
  const float* W0  = (const float*)d_in[2];
  const float* b0  = (const float*)d_in[3];
  const float* g0  = (const float*)d_in[4];
  const float* be0 = (const float*)d_in[5];
  const float* W1  = (const float*)d_in[6];
  const float* b1  = (const float*)d_in[7];
  const float* g1  = (const float*)d_in[8];
  const float* be1 = (const float*)d_in[9];
  const float* Wq  = (const float*)d_in[10];
  const float* bq  = (const float*)d_in[11];
  const float* Wk  = (const float*)d_in[12];
  const float* bk  = (const float*)d_in[13];
  const float* Wv  = (const float*)d_in[14];
  const float* bv  = (const float*)d_in[15];
  const float* gl  = (const float*)d_in[16];
  const float* bl  = (const float*)d_in[17];
  float* out = (float*)d_out;

  u16* h    = (u16*)d_ws;                  // 32MB
  u16* ctxb = h    + (size_t)MM*HH;        // 32MB
  u16* qb   = ctxb + (size_t)MM*HH;        // 32MB
  u16* kb   = qb   + (size_t)MM*HH;        // 32MB
  u16* vb   = kb   + (size_t)MM*HH;        // 32MB
  u16* vT   = vb   + (size_t)MM*HH;        // 32MB
  u16* wt   = vT   + (size_t)MM*HH;        // 352KB (11 x 128 x 128 bf16)

  wt_prep<<<11, 256, 0, stream>>>(W0, W1, Wq, Wk, Wv, wt);

  linear_mfma<true ,true ><<<MM/128, 256, 0, stream>>>(x, wt,           b0, g0, be0, h);
  linear_mfma<false,true ><<<MM/128, 256, 0, stream>>>(h, wt + 1*HH*HH, b1, g1, be1, h);

  for (int d = 0; d < 3; d++) {
    qkv_fused<<<MM/128, 256, 0, stream>>>(
        h, wt + (2+3*d)*HH*HH, bq + d*HH, bk + d*HH, bv + d*HH, qb, kb, vb);
    transpose_v_kernel<<<BB*4, 256, 0, stream>>>(vb, vT);
    attn_kernel<<<BB*2*4, 256, 0, stream>>>(qb, kb, vT, lens, ctxb);
    resln_kernel<<<MM/4, 256, 0, stream>>>(ctxb, h, gl + d*HH, bl + d*HH);
  }
  maxred_kernel<<<BB, 256, 0, stream>>>(h, out);
}